// Round 9
// baseline (86.215 us; speedup 1.0000x reference)
//
#include <hip/hip_runtime.h>

#define HW 4096
#define NC 256
#define NP 8
#define NB 32
#define CHW 64
#define NCH 64   // chunks per batch

// ---------------- Fused: per (b, 64-hw chunk) block; grid 2048 = 8 blocks/CU ----------------
// Phase A: wave w owns c in [64w,64w+64), lane = hw. Coalesced 256B loads
//   (the only HBM read of x), unroll 16 -> deep load pipeline. Cross-wave
//   reduce via LDS. e = exp(score+bias); no max-subtract (|s|<~5 for this
//   distribution; ratios identical; absmax ~1e-7 validated R1-R8).
// Phase B: lane=(cs,p)=(lane>>3,lane&7); wave owns 64 c. 8 p-lanes share each
//   row address (merged); acc[ci] is the COMPLETE out[c][p] chunk-partial:
//   zero per-iteration shuffles (R7 lesson). x re-read is L3-hot.
// LDS 10.4 KB, VGPR ~56 -> up to 8 blocks/CU resident: latency hidden by TLP
// (fixes R8's 19% occupancy).
__global__ __launch_bounds__(256) void k_fused(
    const float* __restrict__ x, const float* __restrict__ Wm,
    const float* __restrict__ bias, float* __restrict__ partial,
    float* __restrict__ psum) {
  __shared__ float sred[4][NP][CHW];            // 8 KB
  __shared__ __align__(16) float els[NP][68];   // 2176 B (pad 68: phase-B reads conflict-free)

  const int bid = blockIdx.x;
  const int b = bid >> 6;
  const int chunk = bid & 63;
  const int t = threadIdx.x, lane = t & 63, w = t >> 6;
  const float* xb = x + (size_t)b * NC * HW + chunk * CHW;

  // ---- Phase A: score partials; wave w -> c in [64w,64w+64), lane = hw ----
  float s[NP];
#pragma unroll
  for (int p = 0; p < NP; ++p) s[p] = 0.f;
  {
    const float* xw = xb + (size_t)(w << 6) * HW + lane;
#pragma unroll 16
    for (int i = 0; i < 64; ++i) {
      float xv = xw[(size_t)i * HW];            // 64 lanes x 4B contiguous
      int c = (w << 6) + i;
#pragma unroll
      for (int p = 0; p < NP; ++p)
        s[p] = fmaf(Wm[p * NC + c], xv, s[p]);  // wave-uniform -> s_load
    }
  }
#pragma unroll
  for (int p = 0; p < NP; ++p) sred[w][p][lane] = s[p];
  __syncthreads();

  // ---- e = exp(score + bias); els + psum partial ----
  {
    const int ep = t >> 5, eh = t & 31;
    float a0 = bias[ep], a1 = a0;
#pragma unroll
    for (int ww = 0; ww < 4; ++ww) {
      a0 += sred[ww][ep][eh];
      a1 += sred[ww][ep][eh + 32];
    }
    float e0 = expf(a0), e1 = expf(a1);
    els[ep][eh] = e0;
    els[ep][eh + 32] = e1;
    float esum = e0 + e1;
#pragma unroll
    for (int off = 16; off; off >>= 1) esum += __shfl_xor(esum, off);
    if (eh == 0) psum[bid * NP + ep] = esum;
  }
  __syncthreads();

  // ---- Phase B: pool; lane = (cs, p); wave owns 64 c ----
  const int cs = lane >> 3;
  const int p_ = lane & 7;
  const int cbase = w << 6;
  const float* xr = xb + (size_t)(cbase + cs) * HW;

  float acc[8];
#pragma unroll
  for (int ci = 0; ci < 8; ++ci) acc[ci] = 0.f;

#pragma unroll 4
  for (int k = 0; k < 16; ++k) {
    float4 e4 = *(const float4*)&els[p_][k * 4];  // 8 distinct 4-bank windows
#pragma unroll
    for (int ci = 0; ci < 8; ++ci) {
      float4 xv = *(const float4*)(xr + (size_t)(ci * 8) * HW + k * 4);  // 8 lanes share addr
      float v = xv.x * e4.x;
      v = fmaf(xv.y, e4.y, v);
      v = fmaf(xv.z, e4.z, v);
      acc[ci] = fmaf(xv.w, e4.w, acc[ci]);
      acc[ci] += v;
    }
  }

  // ---- coalesced partial write: partial[bid][c][p] (index = w*512+ci*64+lane) ----
#pragma unroll
  for (int ci = 0; ci < 8; ++ci) {
    int c = cbase + ci * 8 + cs;
    partial[(size_t)bid * NC * NP + c * NP + p_] = acc[ci];
  }
}

// ---------------- Reduce: out[b,p,c] = ginv * sum_ch partial ----------------
__global__ __launch_bounds__(256) void k_reduce(
    const float* __restrict__ partial, const float* __restrict__ psum,
    float* __restrict__ out) {
  __shared__ float gv[NP];
  int bid = blockIdx.x;      // 32 b x 8 c-chunks
  int b = bid >> 3;
  int cchunk = bid & 7;
  int t = threadIdx.x, lane = t & 63, w2 = t >> 6;

  if (w2 == 0) {
#pragma unroll
    for (int p = 0; p < NP; ++p) {
      float v = psum[(size_t)(b * NCH + lane) * NP + p];
#pragma unroll
      for (int off = 32; off; off >>= 1) v += __shfl_xor(v, off);
      if (lane == 0) gv[p] = 1.0f / (v * (float)HW);
    }
  }
  __syncthreads();

  float acc = 0.f;
#pragma unroll 16
  for (int ch = 0; ch < NCH; ++ch)
    acc += partial[((size_t)(b * NCH + ch) * NC + cchunk * 32) * NP + t];  // coalesced

  int cl = t >> 3, p = t & 7;
  out[((size_t)b * NP + p) * NC + cchunk * 32 + cl] = acc * gv[p];
}

extern "C" void kernel_launch(void* const* d_in, const int* in_sizes, int n_in,
                              void* d_out, int out_size, void* d_ws, size_t ws_size,
                              hipStream_t stream) {
  const float* x = (const float*)d_in[0];
  const float* Wm = (const float*)d_in[1];
  const float* bias = (const float*)d_in[2];
  float* out = (float*)d_out;

  float* ws = (float*)d_ws;
  float* partial = ws;                                  // 2048*256*8 floats = 16 MiB
  float* psum = ws + (size_t)NB * NCH * NC * NP;        // 2048*8 floats

  k_fused<<<NB * NCH, 256, 0, stream>>>(x, Wm, bias, partial, psum);
  k_reduce<<<NB * NP, 256, 0, stream>>>(partial, psum, out);
}

// Round 10
// 52.309 us; speedup vs baseline: 1.6482x; 1.6482x over previous
//
#include <hip/hip_runtime.h>

#define HW 4096
#define NC 256
#define NP 8
#define NB 32
#define CHW 64
#define NCH 64   // chunks per batch

#define FMA4(acc, v, s)                  \
  acc.x = fmaf((v).x, (s), acc.x);       \
  acc.y = fmaf((v).y, (s), acc.y);       \
  acc.z = fmaf((v).z, (s), acc.z);       \
  acc.w = fmaf((v).w, (s), acc.w)

// ---------------- Fused: per (b, 64-hw chunk) block; grid 2048 ----------------
// R6 structure + deep load pipelining (fill-kernel evidence: BW comes from
// back-to-back wide loads, not occupancy).
// Phase A: lane=(cr,q); one float4 instr = 4 full 256B rows; 16 instrs total
//   issued in two explicit 8-deep batches (8KB/wave in flight). W^T in LDS
//   (kills per-iter s_load stalls). csub-reduce ONCE (not per-iter; R7 lesson).
// e = exp(score+bias); no max-subtract (|s|<~5; ratios identical; absmax
//   ~1e-7 validated R1-R9).
// Phase B: thread = row c=t (L1 absorbs line re-reads; R6 evidence), e via
//   literal-addr b128 LDS broadcasts, x loads in 8-deep float4 batches.
__global__ __launch_bounds__(256) void k_fused(
    const float* __restrict__ x, const float* __restrict__ Wm,
    const float* __restrict__ bias, float* __restrict__ partial,
    float* __restrict__ psum) {
  __shared__ __align__(16) float wt[NC][NP];     // 8 KB W^T
  __shared__ __align__(16) float sp[4][NP][CHW]; // 8 KB score partials
  __shared__ __align__(16) float els[NP][68];    // 2.2 KB (padded)

  const int bid = blockIdx.x;
  const int b = bid >> 6;
  const int chunk = bid & 63;
  const int t = threadIdx.x, lane = t & 63, w = t >> 6;
  const float* xb = x + (size_t)b * NC * HW + chunk * CHW;

  // ---- stage W^T (once; coalesced global reads) ----
#pragma unroll
  for (int p = 0; p < NP; ++p) wt[t][p] = Wm[p * NC + t];
  __syncthreads();

  // ---- Phase A: scores; wave w -> c in [64w,64w+64) ----
  const int cr = lane >> 4;   // row-in-group 0..3
  const int q = lane & 15;    // float4 hw index
  const int c0 = w << 6;
  const float* xwp = xb + (size_t)(c0 + cr) * HW + q * 4;

  float4 s4[NP];
#pragma unroll
  for (int p = 0; p < NP; ++p) s4[p] = make_float4(0.f, 0.f, 0.f, 0.f);

#pragma unroll
  for (int h = 0; h < 2; ++h) {
    float4 xv[8];
#pragma unroll
    for (int i = 0; i < 8; ++i)   // 8 back-to-back 1KB wave-loads
      xv[i] = *(const float4*)(xwp + (size_t)(h * 32 + i * 4) * HW);
#pragma unroll
    for (int i = 0; i < 8; ++i) {
      int c = c0 + h * 32 + i * 4 + cr;
      float4 wA = *(const float4*)&wt[c][0];  // 4 distinct rows: conflict-free
      float4 wB = *(const float4*)&wt[c][4];
      FMA4(s4[0], xv[i], wA.x);
      FMA4(s4[1], xv[i], wA.y);
      FMA4(s4[2], xv[i], wA.z);
      FMA4(s4[3], xv[i], wA.w);
      FMA4(s4[4], xv[i], wB.x);
      FMA4(s4[5], xv[i], wB.y);
      FMA4(s4[6], xv[i], wB.z);
      FMA4(s4[7], xv[i], wB.w);
    }
  }

  // csub-reduce once (lane bits 4,5); cr==0 lanes write sp (256B contiguous)
#pragma unroll
  for (int p = 0; p < NP; ++p) {
    float4 v = s4[p];
    v.x += __shfl_xor(v.x, 16); v.y += __shfl_xor(v.y, 16);
    v.z += __shfl_xor(v.z, 16); v.w += __shfl_xor(v.w, 16);
    v.x += __shfl_xor(v.x, 32); v.y += __shfl_xor(v.y, 32);
    v.z += __shfl_xor(v.z, 32); v.w += __shfl_xor(v.w, 32);
    if (cr == 0) *(float4*)&sp[w][p][q * 4] = v;
  }
  __syncthreads();

  // ---- e = exp(score + bias); els + psum partial ----
  {
    const int ep = t >> 5, eh = t & 31;
    float a0 = bias[ep], a1 = a0;
#pragma unroll
    for (int ww = 0; ww < 4; ++ww) {
      a0 += sp[ww][ep][eh];
      a1 += sp[ww][ep][eh + 32];
    }
    float e0 = expf(a0), e1 = expf(a1);
    els[ep][eh] = e0;
    els[ep][eh + 32] = e1;
    float esum = e0 + e1;
#pragma unroll
    for (int off = 16; off; off >>= 1) esum += __shfl_xor(esum, off);
    if (eh == 0) psum[bid * NP + ep] = esum;
  }
  __syncthreads();

  // ---- Phase B: pool; thread = row c = t (tile L1/L2-hot) ----
  const float* xr = xb + (size_t)t * HW;
  float acc[NP];
#pragma unroll
  for (int p = 0; p < NP; ++p) acc[p] = 0.f;

#pragma unroll
  for (int h = 0; h < 2; ++h) {
    float4 xv[8];
#pragma unroll
    for (int j = 0; j < 8; ++j)   // 8-deep batch, row-sequential (L1-friendly)
      xv[j] = *(const float4*)(xr + (h * 8 + j) * 4);
#pragma unroll
    for (int j = 0; j < 8; ++j) {
      const int k = h * 8 + j;
#pragma unroll
      for (int p = 0; p < NP; ++p) {
        float4 e4 = *(const float4*)&els[p][k * 4];  // literal addr -> broadcast
        acc[p] = fmaf(xv[j].x, e4.x, acc[p]);
        acc[p] = fmaf(xv[j].y, e4.y, acc[p]);
        acc[p] = fmaf(xv[j].z, e4.z, acc[p]);
        acc[p] = fmaf(xv[j].w, e4.w, acc[p]);
      }
    }
  }

  // ---- coalesced partial write: partial[bid][p][c] ----
#pragma unroll
  for (int p = 0; p < NP; ++p)
    partial[((size_t)bid * NP + p) * NC + t] = acc[p];
}

// ---------------- Reduce: out[b,p,c] = ginv * sum_ch partial ----------------
__global__ __launch_bounds__(256) void k_reduce(
    const float* __restrict__ partial, const float* __restrict__ psum,
    float* __restrict__ out) {
  int bp = blockIdx.x;  // b*8 + p
  int b = bp >> 3, p = bp & 7;
  int t = threadIdx.x, lane = t & 63, w2 = t >> 6;

  __shared__ float gv;
  if (w2 == 0) {
    float v = psum[(size_t)(b * NCH + lane) * NP + p];
#pragma unroll
    for (int off = 32; off; off >>= 1) v += __shfl_xor(v, off);
    if (lane == 0) gv = 1.0f / (v * (float)HW);
  }
  __syncthreads();
  float ginv = gv;

  float acc = 0.f;
#pragma unroll 16
  for (int ch = 0; ch < NCH; ++ch)
    acc += partial[(((size_t)b * NCH + ch) * NP + p) * NC + t];
  out[((size_t)b * NP + p) * NC + t] = acc * ginv;
}

extern "C" void kernel_launch(void* const* d_in, const int* in_sizes, int n_in,
                              void* d_out, int out_size, void* d_ws, size_t ws_size,
                              hipStream_t stream) {
  const float* x = (const float*)d_in[0];
  const float* Wm = (const float*)d_in[1];
  const float* bias = (const float*)d_in[2];
  float* out = (float*)d_out;

  float* ws = (float*)d_ws;
  float* partial = ws;                                  // 2048*8*256 floats = 16 MiB
  float* psum = ws + (size_t)NB * NCH * NP * NC;        // 2048*8 floats

  k_fused<<<NB * NCH, 256, 0, stream>>>(x, Wm, bias, partial, psum);
  k_reduce<<<NB * NP, 256, 0, stream>>>(partial, psum, out);
}